// Round 2
// baseline (318.794 us; speedup 1.0000x reference)
//
#include <hip/hip_runtime.h>

// 3-level db4 band-split. R3: tile-parallel rewrite.
// Each block = one 1024-sample output tile of one row (8 tiles/row, 16384 blocks,
// T=256). All windows (with halo) live in 12.3 KB LDS -> 8 blocks/CU = 32 waves/CU
// full occupancy. Support radius: y[n] depends on x[n-50..n+46] -> halo 48/56.
// Symmetric reflection handled by "reflected slot" scheme: out-of-range window
// slots hold the value of the reflected index, so all interior reads are raw.

#define T      256
#define N0     8192
#define L1     4099
#define L2     2053
#define L3     1030
#define NROWS  2048
#define TW     1024

#define RL0 0.23037781330885523f
#define RL1 0.7148465705525415f
#define RL2 0.6308807679295904f
#define RL3 (-0.02798376941698385f)
#define RL4 (-0.18703481171888114f)
#define RL5 0.030841381835986965f
#define RL6 0.032883011666982945f
#define RL7 (-0.010597401784997278f)

__device__ __forceinline__ int reflect(int m, int n)
{
    m = (m < 0) ? (-1 - m) : m;
    m = (m >= n) ? (2 * n - 1 - m) : m;
    return m;
}

// Forward DWT over a window: dstA/dstD[idx] = coefficients at global index
// (out_lo+idx), reflected into [0,Lv) when out of range. Reads src window
// (base global index src_lo) at raw indices 2*ge-6 .. 2*ge+1 (always in window).
__device__ __forceinline__ void fwd_win(const float* __restrict__ src, int src_lo,
                                        float* __restrict__ dstA, float* __restrict__ dstD,
                                        int out_lo, int out_len, int Lv, int tid)
{
    const float lo[8] = {RL0, RL1, RL2, RL3, RL4, RL5, RL6, RL7};
    const float hi[8] = {RL7, -RL6, RL5, -RL4, RL3, -RL2, RL1, -RL0};
    for (int idx = tid; idx < out_len; idx += T) {
        int g  = out_lo + idx;
        int ge = reflect(g, Lv);
        int b  = 2 * ge - 6 - src_lo;
        float sa = 0.f, sd = 0.f;
#pragma unroll
        for (int k = 0; k < 8; ++k) {
            float v = src[b + k];
            sa = fmaf(v, lo[k], sa);
            sd = fmaf(v, hi[k], sd);
        }
        dstA[idx] = sa;
        dstD[idx] = sd;
    }
}

// Upsample-conv LDS->LDS. Output pair p=2t,2t+1 for t = t0+idx, idx in [0,pairs).
// dst window base = 2*t0 (slot 2*idx). r[2t]=sum s[t+k]*e[k]; r[2t+1]=sum s[t+k]*o[k].
__device__ __forceinline__ void up_win(const float* __restrict__ src, int src_lo,
                                       float* __restrict__ dst, int t0, int pairs,
                                       float o0, float o1, float o2, float o3,
                                       float e0, float e1, float e2, float e3, int tid)
{
    for (int idx = tid; idx < pairs; idx += T) {
        int b = t0 + idx - src_lo;
        float s0 = src[b], s1 = src[b + 1], s2 = src[b + 2], s3 = src[b + 3];
        float ev = s0 * e0 + s1 * e1 + s2 * e2 + s3 * e3;
        float od = s0 * o0 + s1 * o1 + s2 * o2 + s3 * o3;
        ((float2*)dst)[idx] = make_float2(ev, od);
    }
}

// Final upsample-conv to global: thread tid produces n = n0+4*tid .. +3 (float4).
// Reads src raw indices n0/2+2*tid .. +4 (window base src_lo).
__device__ __forceinline__ void fin_win(const float* __restrict__ src, int src_lo, int n0,
                                        float* __restrict__ g,
                                        float o0, float o1, float o2, float o3,
                                        float e0, float e1, float e2, float e3, int tid)
{
    int b = (n0 >> 1) + 2 * tid - src_lo;
    float s0 = src[b], s1 = src[b + 1], s2 = src[b + 2], s3 = src[b + 3], s4 = src[b + 4];
    float4 o;
    o.x = s0 * e0 + s1 * e1 + s2 * e2 + s3 * e3;
    o.y = s0 * o0 + s1 * o1 + s2 * o2 + s3 * o3;
    o.z = s1 * e0 + s2 * e1 + s3 * e2 + s4 * e3;
    o.w = s1 * o0 + s2 * o1 + s3 * o2 + s4 * o3;
    ((float4*)(g + n0))[tid] = o;
}

// LDS pool (floats). Windows per tile (n0 = tile*1024, n1 = n0+1024):
//   a1/d1: [n0/2-18, n1/2+28)  len 558   a2/d2: [n0/4-6, n1/4+14) len 276
//   a3/d3: [n0/8,   n1/8+7)    len 135   x:     [n0-48,  n1+56)   len 1128
// Temps alias xw after P1: t2 [n0/2,+516), t1a/t1d [n0/4,+262); t2d aliases a1w.
#define POOL_F 3088

__global__ __launch_bounds__(T) void wavelet_bands(const float* __restrict__ x,
                                                   float* __restrict__ out)
{
    __shared__ float buf[POOL_F];
    const int tid  = threadIdx.x;
    const int bid  = blockIdx.x;
    const int row  = bid >> 3;
    const int tile = bid & 7;
    const int n0   = tile * TW;

    const int lo1 = (n0 >> 1) - 18;
    const int lo2 = (n0 >> 2) - 6;
    const int lo3 = (n0 >> 3);
    const int lox = n0 - 48;

    float* a1w = buf;            // 560
    float* d1w = buf + 560;      // 560
    float* a2w = buf + 1120;     // 280
    float* d2w = buf + 1400;     // 280
    float* a3w = buf + 1680;     // 136
    float* d3w = buf + 1816;     // 136
    float* xw  = buf + 1952;     // 1136
    float* t2  = xw;             // 520  (alias, live P3..P6)
    float* t1a = xw + 520;       // 264  (live P4..P5)
    float* t1d = xw + 784;       // 264  (live P4..P5)
    float* t2d = buf;            // 520  (aliases a1w, live P5..P6)

    const float* xr = x + (size_t)row * N0;
    const size_t band = (size_t)NROWS * N0;
    float* o0p = out + (size_t)row * N0;   // a3 band
    float* o1p = o0p + band;               // d3
    float* o2p = o0p + 2 * band;           // d2
    float* o3p = o0p + 3 * band;           // d1

    // P0: stage x window (reflected at row edges; interior tiles branch-free)
    for (int idx = tid; idx < 1128; idx += T)
        xw[idx] = xr[reflect(lox + idx, N0)];
    __syncthreads();

    // P1: level-1 forward (x -> a1,d1 windows)
    fwd_win(xw, lox, a1w, d1w, lo1, 558, L1, tid);
    __syncthreads();

    // P2: level-2 forward  ||  d1 band final -> o3
    fwd_win(a1w, lo1, a2w, d2w, lo2, 276, L2, tid);
    fin_win(d1w, lo1, n0, o3p, -RL0, -RL2, -RL4, -RL6, RL1, RL3, RL5, RL7, tid);
    __syncthreads();

    // P3: level-3 forward  ||  d2 stage-1: up_HI(d2) -> t2
    fwd_win(a2w, lo2, a3w, d3w, lo3, 135, L3, tid);
    up_win(d2w, lo2, t2, n0 >> 2, 258, -RL0, -RL2, -RL4, -RL6, RL1, RL3, RL5, RL7, tid);
    __syncthreads();

    // P4: d2 band final -> o2  ||  up_LO(a3) -> t1a  ||  up_HI(d3) -> t1d
    fin_win(t2, n0 >> 1, n0, o2p, RL7, RL5, RL3, RL1, RL6, RL4, RL2, RL0, tid);
    up_win(a3w, lo3, t1a, n0 >> 3, 131, RL7, RL5, RL3, RL1, RL6, RL4, RL2, RL0, tid);
    up_win(d3w, lo3, t1d, n0 >> 3, 131, -RL0, -RL2, -RL4, -RL6, RL1, RL3, RL5, RL7, tid);
    __syncthreads();

    // P5: a3 stage-2: t1a -> t2  ||  d3 stage-2: t1d -> t2d
    up_win(t1a, n0 >> 2, t2,  n0 >> 2, 258, RL7, RL5, RL3, RL1, RL6, RL4, RL2, RL0, tid);
    up_win(t1d, n0 >> 2, t2d, n0 >> 2, 258, RL7, RL5, RL3, RL1, RL6, RL4, RL2, RL0, tid);
    __syncthreads();

    // P6: a3 band final -> o0  ||  d3 band final -> o1
    fin_win(t2,  n0 >> 1, n0, o0p, RL7, RL5, RL3, RL1, RL6, RL4, RL2, RL0, tid);
    fin_win(t2d, n0 >> 1, n0, o1p, RL7, RL5, RL3, RL1, RL6, RL4, RL2, RL0, tid);
}

extern "C" void kernel_launch(void* const* d_in, const int* in_sizes, int n_in,
                              void* d_out, int out_size, void* d_ws, size_t ws_size,
                              hipStream_t stream)
{
    const float* x = (const float*)d_in[0];
    float* out = (float*)d_out;
    wavelet_bands<<<NROWS * 8, T, 0, stream>>>(x, out);
}

// Round 3
// 311.389 us; speedup vs baseline: 1.0238x; 1.0238x over previous
//
#include <hip/hip_runtime.h>

// 3-level db4 band-split. R4: barrier-free wave-autonomous tiles.
// One WAVE owns one 256-sample output tile end-to-end; all intermediates live
// in a private 960-float LDS slice. No __syncthreads anywhere: every LDS
// dependency is wave-internal (program order + compiler lgkmcnt waits).
// 65536 independent waves, 16384 blocks x 256 thr (4 waves/block),
// 15.36 KB LDS/block -> 8 blocks/CU = 32 waves/CU, zero sync coupling.
// Halo: y[n] depends on x[n-50..n+46]; per-tile windows carry reflected-slot
// values so interior reads are raw (index math verified in R3, re-parametrized).

#define T      256
#define N0     8192
#define L1     4099
#define L2     2053
#define L3     1030
#define NROWS  2048
#define TW     256        // outputs per wave
#define WSLICE 960        // LDS floats per wave (16B-aligned slice)

#define RL0 0.23037781330885523f
#define RL1 0.7148465705525415f
#define RL2 0.6308807679295904f
#define RL3 (-0.02798376941698385f)
#define RL4 (-0.18703481171888114f)
#define RL5 0.030841381835986965f
#define RL6 0.032883011666982945f
#define RL7 (-0.010597401784997278f)

__device__ __forceinline__ int reflect(int m, int n)
{
    m = (m < 0) ? (-1 - m) : m;
    m = (m >= n) ? (2 * n - 1 - m) : m;
    return m;
}

// Forward DWT over a window: dstA/dstD[idx] = coeff at global index out_lo+idx
// (reflected into [0,Lv)). Reads src window (base src_lo) at raw even index
// 2*ge-6 .. 2*ge+1 -> 4x float2 (window bases all even).
__device__ __forceinline__ void fwd_win(const float* __restrict__ src, int src_lo,
                                        float* __restrict__ dstA, float* __restrict__ dstD,
                                        int out_lo, int out_len, int Lv, int lane)
{
    const float lo[8] = {RL0, RL1, RL2, RL3, RL4, RL5, RL6, RL7};
    const float hi[8] = {RL7, -RL6, RL5, -RL4, RL3, -RL2, RL1, -RL0};
    const float2* s2 = (const float2*)src;
    for (int idx = lane; idx < out_len; idx += 64) {
        int g  = out_lo + idx;
        int ge = reflect(g, Lv);
        int h  = (2 * ge - 6 - src_lo) >> 1;
        float2 p0 = s2[h], p1 = s2[h + 1], p2 = s2[h + 2], p3 = s2[h + 3];
        float w[8] = {p0.x, p0.y, p1.x, p1.y, p2.x, p2.y, p3.x, p3.y};
        float sa = 0.f, sd = 0.f;
#pragma unroll
        for (int k = 0; k < 8; ++k) {
            sa = fmaf(w[k], lo[k], sa);
            sd = fmaf(w[k], hi[k], sd);
        }
        dstA[idx] = sa;
        dstD[idx] = sd;
    }
}

// Upsample-conv LDS->LDS. Pair p=2t,2t+1 for t=t0+idx, idx in [0,pairs).
// dst window base = global 2*t0 (slot 2*idx).
__device__ __forceinline__ void up_win(const float* __restrict__ src, int src_lo,
                                       float* __restrict__ dst, int t0, int pairs,
                                       float o0, float o1, float o2, float o3,
                                       float e0, float e1, float e2, float e3, int lane)
{
    for (int idx = lane; idx < pairs; idx += 64) {
        int b = t0 + idx - src_lo;
        float s0 = src[b], s1 = src[b + 1], s2 = src[b + 2], s3 = src[b + 3];
        float ev = s0 * e0 + s1 * e1 + s2 * e2 + s3 * e3;
        float od = s0 * o0 + s1 * o1 + s2 * o2 + s3 * o3;
        ((float2*)dst)[idx] = make_float2(ev, od);
    }
}

// Final upsample-conv to global: lane produces n = w0+4*lane .. +3 (one float4).
// Reads src raw b = w0/2 + 2*lane - src_lo (even), i.e. 2x float2 + 1 scalar.
__device__ __forceinline__ void fin_win(const float* __restrict__ src, int src_lo, int w0,
                                        float* __restrict__ g,
                                        float o0, float o1, float o2, float o3,
                                        float e0, float e1, float e2, float e3, int lane)
{
    int b = (w0 >> 1) + 2 * lane - src_lo;
    const float2* s2 = (const float2*)src;
    float2 q0 = s2[b >> 1], q1 = s2[(b >> 1) + 1];
    float s4 = src[b + 4];
    float a0 = q0.x, a1 = q0.y, a2 = q1.x, a3 = q1.y;
    float4 o;
    o.x = a0 * e0 + a1 * e1 + a2 * e2 + a3 * e3;
    o.y = a0 * o0 + a1 * o1 + a2 * o2 + a3 * o3;
    o.z = a1 * e0 + a2 * e1 + a3 * e2 + s4 * e3;
    o.w = a1 * o0 + a2 * o1 + a3 * o2 + s4 * o3;
    ((float4*)(g + w0))[lane] = o;
}

// Per-wave LDS slice layout (floats, all window bases even; slice 16B-aligned):
//   xw   [0,360)    x window [w0-48, w0+312)            live P0-P1
//   a1w  [360,534)  a1 [w0/2-18, +174)                  live P1-P2
//   d1w  [534,708)  d1 same range                       live P1-P2
//   a2w  [708,792)  a2 [w0/4-6, +84)                    live P2-P3
//   d2w  [792,876)  d2 same                             live P2-P3
//   a3w  [876,915)  a3 [w0/8, +39)                      live P3-P4
//   d3w  [915,954)  d3 same                             live P3-P4
//   t2   [0,132)    up_HI(d2), level-1 grid [w0/2,+132) live P3-P4 (xw dead)
//   t1a  [136,206)  up_LO(a3), level-2 grid [w0/4,+70)  live P4-P5
//   t1d  [208,278)  up_HI(d3)                           live P4-P5
//   t2a  [360,492)  up_LO(t1a)                          live P5-P6 (a1w dead)
//   t2d  [534,666)  up_LO(t1d)                          live P5-P6 (d1w dead)

__global__ __launch_bounds__(T) void wavelet_bands(const float* __restrict__ x,
                                                   float* __restrict__ out)
{
    __shared__ float buf[4 * WSLICE];
    const int tid  = threadIdx.x;
    const int lane = tid & 63;
    const int wid  = tid >> 6;
    const int bid  = blockIdx.x;
    const int row  = bid >> 3;
    const int w0   = ((bid & 7) * 4 + wid) * TW;

    float* wbuf = buf + wid * WSLICE;
    float* xw  = wbuf;
    float* a1w = wbuf + 360;
    float* d1w = wbuf + 534;
    float* a2w = wbuf + 708;
    float* d2w = wbuf + 792;
    float* a3w = wbuf + 876;
    float* d3w = wbuf + 915;
    float* t2  = wbuf;
    float* t1a = wbuf + 136;
    float* t1d = wbuf + 208;
    float* t2a = wbuf + 360;
    float* t2d = wbuf + 534;

    const int lo1 = (w0 >> 1) - 18;
    const int lo2 = (w0 >> 2) - 6;
    const int lo3 = (w0 >> 3);
    const int lox = w0 - 48;

    const float* xr = x + (size_t)row * N0;
    const size_t band = (size_t)NROWS * N0;
    float* o0p = out + (size_t)row * N0;   // a3 band
    float* o1p = o0p + band;               // d3
    float* o2p = o0p + 2 * band;           // d2
    float* o3p = o0p + 3 * band;           // d1

    // P0: stage x window. Only first/last tile of a row reflects (wave-uniform).
    if (w0 == 0 || w0 == N0 - TW) {
        for (int idx = lane; idx < 360; idx += 64)
            xw[idx] = xr[reflect(lox + idx, N0)];
    } else {
        const float4* xr4 = (const float4*)xr;
        float4* xw4 = (float4*)xw;
        const int q0 = lox >> 2;
        for (int i = lane; i < 90; i += 64)
            xw4[i] = xr4[q0 + i];
    }

    // P1: level-1 forward (x -> a1,d1)
    fwd_win(xw, lox, a1w, d1w, lo1, TW / 2 + 46, L1, lane);

    // P2: level-2 forward  ||  d1 band final -> o3
    fwd_win(a1w, lo1, a2w, d2w, lo2, TW / 4 + 20, L2, lane);
    fin_win(d1w, lo1, w0, o3p, -RL0, -RL2, -RL4, -RL6, RL1, RL3, RL5, RL7, lane);

    // P3: level-3 forward  ||  d2 stage-1: up_HI(d2) -> t2
    fwd_win(a2w, lo2, a3w, d3w, lo3, TW / 8 + 7, L3, lane);
    up_win(d2w, lo2, t2, w0 >> 2, TW / 4 + 2, -RL0, -RL2, -RL4, -RL6, RL1, RL3, RL5, RL7, lane);

    // P4: d2 band final -> o2  ||  up_LO(a3) -> t1a  ||  up_HI(d3) -> t1d
    fin_win(t2, w0 >> 1, w0, o2p, RL7, RL5, RL3, RL1, RL6, RL4, RL2, RL0, lane);
    up_win(a3w, lo3, t1a, w0 >> 3, TW / 8 + 3, RL7, RL5, RL3, RL1, RL6, RL4, RL2, RL0, lane);
    up_win(d3w, lo3, t1d, w0 >> 3, TW / 8 + 3, -RL0, -RL2, -RL4, -RL6, RL1, RL3, RL5, RL7, lane);

    // P5: stage-2 ups: t1a -> t2a  ||  t1d -> t2d
    up_win(t1a, w0 >> 2, t2a, w0 >> 2, TW / 4 + 2, RL7, RL5, RL3, RL1, RL6, RL4, RL2, RL0, lane);
    up_win(t1d, w0 >> 2, t2d, w0 >> 2, TW / 4 + 2, RL7, RL5, RL3, RL1, RL6, RL4, RL2, RL0, lane);

    // P6: a3 band final -> o0  ||  d3 band final -> o1
    fin_win(t2a, w0 >> 1, w0, o0p, RL7, RL5, RL3, RL1, RL6, RL4, RL2, RL0, lane);
    fin_win(t2d, w0 >> 1, w0, o1p, RL7, RL5, RL3, RL1, RL6, RL4, RL2, RL0, lane);
}

extern "C" void kernel_launch(void* const* d_in, const int* in_sizes, int n_in,
                              void* d_out, int out_size, void* d_ws, size_t ws_size,
                              hipStream_t stream)
{
    const float* x = (const float*)d_in[0];
    float* out = (float*)d_out;
    wavelet_bands<<<NROWS * 8, T, 0, stream>>>(x, out);
}